// Round 4
// baseline (12773.936 us; speedup 1.0000x reference)
//
#include <hip/hip_runtime.h>
#include <cfloat>

#define NRW 32768
#define KC 4096
#define CD 256
#define HW 1024

// exact numpy fp32 MAC: mul and add separately rounded (contract off in kernel)
#define MAC4(accv, xv, ev) do { \
  float p0 = (xv).x * (ev).x; (accv).x = (accv).x + p0; \
  float p1 = (xv).y * (ev).y; (accv).y = (accv).y + p1; \
  float p2 = (xv).z * (ev).z; (accv).z = (accv).z + p2; \
  float p3 = (xv).w * (ev).w; (accv).w = (accv).w + p3; } while (0)

// ---------- se[k] = np.sum(cb[k]**2) : numpy pairwise (128+128, scalar 8-acc) ----------
__global__ __launch_bounds__(256) void vq_se(const float* __restrict__ cb,
                                             float* __restrict__ se) {
#pragma clang fp contract(off)
  const int tid = threadIdx.x;
  const int g = tid >> 3;
  const int j = tid & 7;
  const int code = blockIdx.x * 32 + g;
  const float* e = cb + (size_t)code * CD;
  float half[2];
#pragma unroll
  for (int h = 0; h < 2; ++h) {
    const float* a = e + h * 128;
    float v = a[j];
    float r = v * v;
#pragma unroll
    for (int i = 1; i < 16; ++i) {
      float w = a[8 * i + j];
      float w2 = w * w;
      r = r + w2;
    }
    float l1 = r + __shfl_down(r, 1, 8);
    float l2 = l1 + __shfl_down(l1, 2, 8);
    float l3 = l2 + __shfl_down(l2, 4, 8);
    half[h] = l3;
  }
  if (j == 0) se[code] = half[0] + half[1];
}

// ---------- main: register-tiled (8 rows x 4 codes per lane), bit-exact np fp32 ----------
__global__ __launch_bounds__(256, 2) void vq_dist(const float* __restrict__ x,
                                                  const float* __restrict__ cb,
                                                  const float* __restrict__ se,
                                                  float* __restrict__ outids) {
#pragma clang fp contract(off)
  __shared__ float xs[32][256];    // 32 KB  [row][c]
  __shared__ float es[256 * 32];   // 32 KB  one c-chunk of 256 codes, XOR-swizzled

  const int tid = threadIdx.x;
  const int l   = tid & 63;        // lane
  const int w   = tid >> 6;        // wave -> rows 8w..8w+7
  const int swz = l & 7;
  const int b   = blockIdx.x >> 5;
  const int hw0 = (blockIdx.x & 31) << 5;
  const float* xb = x + (size_t)b * CD * HW + hw0;

  // ---- stage x: thread tid handles channel c=tid, float4 over hw ----
  {
    const float* src = xb + (size_t)tid * HW;
#pragma unroll
    for (int f = 0; f < 8; ++f) {
      const float4 v = *(const float4*)(src + 4 * f);
      xs[4 * f + 0][tid] = v.x;
      xs[4 * f + 1][tid] = v.y;
      xs[4 * f + 2][tid] = v.z;
      xs[4 * f + 3][tid] = v.w;
    }
  }
  __syncthreads();

  // ---- sx[r] = np.sum(xf[r]**2): numpy pairwise (8-lane group per row) ----
  {
    const int r = tid >> 3, j = tid & 7;
    float half[2];
#pragma unroll
    for (int h = 0; h < 2; ++h) {
      const float* a = &xs[r][h * 128];
      float v = a[j];
      float s = v * v;
#pragma unroll
      for (int i = 1; i < 16; ++i) {
        float ww = a[8 * i + j];
        float w2 = ww * ww;
        s = s + w2;
      }
      float l1 = s + __shfl_down(s, 1, 8);
      float l2 = l1 + __shfl_down(l1, 2, 8);
      float l3 = l2 + __shfl_down(l2, 4, 8);
      half[h] = l3;
    }
    if (j == 0) es[r] = half[0] + half[1];   // scratch in es
  }
  __syncthreads();

  float sx[8];
#pragma unroll
  for (int r = 0; r < 8; ++r) sx[r] = es[8 * w + r];   // broadcast reads

  // ---- per-lane constants ----
  const float* pe[4];
#pragma unroll
  for (int s = 0; s < 4; ++s) pe[s] = es + (s * 64 + l) * 32;
  int foff[8];
#pragma unroll
  for (int f = 0; f < 8; ++f) foff[f] = (f ^ swz) << 2;
  const float* pxw = &xs[8 * w][0];

  float4 acc[8][4];
  float m1[8];
  int   mi[8];
#pragma unroll
  for (int r = 0; r < 8; ++r) {
    m1[r] = FLT_MAX; mi[r] = 0;
#pragma unroll
    for (int s = 0; s < 4; ++s) { acc[r][s].x = 0.f; acc[r][s].y = 0.f; acc[r][s].z = 0.f; acc[r][s].w = 0.f; }
  }

  // ---- preload chunk 0 (ks=0, cc=0) into regs ----
  float4 st[8];
  {
    const float* src = cb + (size_t)tid * CD;
#pragma unroll
    for (int f = 0; f < 8; ++f) st[f] = *(const float4*)(src + 4 * f);
  }

  float se_reg[4];

#pragma unroll 1
  for (int ks = 0; ks < 16; ++ks) {
#pragma unroll
    for (int s = 0; s < 4; ++s) se_reg[s] = se[ks * 256 + s * 64 + l];

#pragma unroll 1
    for (int cc = 0; cc < 8; ++cc) {
      __syncthreads();               // all es readers done
      // write staged chunk (swizzled)
      {
        float* dst = es + tid * 32;
#pragma unroll
        for (int f = 0; f < 8; ++f)
          *(float4*)(dst + ((f ^ (tid & 7)) << 2)) = st[f];
      }
      // issue next-chunk global loads (overlap with compute below)
      const int q = ks * 8 + cc + 1;
      if (q < 128) {
        const float* src = cb + (size_t)((q >> 3) * 256 + tid) * CD + (q & 7) * 32;
#pragma unroll
        for (int f = 0; f < 8; ++f) st[f] = *(const float4*)(src + 4 * f);
      }
      __syncthreads();               // es chunk ready
      // compute: B-blocks {2cc, 2cc+1}, j = 3..0  (exact numpy order)
      const float* px = pxw + 32 * cc;
#pragma unroll
      for (int B2 = 0; B2 < 2; ++B2) {
#pragma unroll
        for (int j = 3; j >= 0; --j) {
          const int f = 4 * B2 + j;
          float4 xv[8], ev[4];
#pragma unroll
          for (int r = 0; r < 8; ++r) xv[r] = *(const float4*)(px + r * 256 + 4 * f);
#pragma unroll
          for (int s = 0; s < 4; ++s) ev[s] = *(const float4*)(pe[s] + foff[f]);
#pragma unroll
          for (int r = 0; r < 8; ++r) {
            MAC4(acc[r][0], xv[r], ev[0]);
            MAC4(acc[r][1], xv[r], ev[1]);
            MAC4(acc[r][2], xv[r], ev[2]);
            MAC4(acc[r][3], xv[r], ev[3]);
          }
        }
      }
    }

    // epilogue: finish 32 dots, update running first-min
#pragma unroll
    for (int r = 0; r < 8; ++r) {
#pragma unroll
      for (int s = 0; s < 4; ++s) {
        const float dot  = (acc[r][s].x + acc[r][s].y) + (acc[r][s].z + acc[r][s].w);
        const float sq   = se_reg[s] + sx[r];
        const float td   = 2.0f * dot;
        const float dist = sq - td;
        const int k = ks * 256 + s * 64 + l;
        if (dist < m1[r]) { m1[r] = dist; mi[r] = k; }   // codes ascend -> first-min
        acc[r][s].x = 0.f; acc[r][s].y = 0.f; acc[r][s].z = 0.f; acc[r][s].w = 0.f;
      }
    }
  }

  // ---- cross-lane argmin (first-index tiebreak), rows disjoint per wave ----
#pragma unroll
  for (int r = 0; r < 8; ++r) {
    float v = m1[r];
    int   idx = mi[r];
#pragma unroll
    for (int off = 32; off > 0; off >>= 1) {
      const float ov = __shfl_xor(v, off, 64);
      const int   oi = __shfl_xor(idx, off, 64);
      if (ov < v || (ov == v && oi < idx)) { v = ov; idx = oi; }
    }
    if (l == 0) outids[b * HW + hw0 + 8 * w + r] = (float)idx;
  }
}

// ---------- emb gather ----------
__global__ __launch_bounds__(256) void vq_emb_out(const float* __restrict__ outids,
                                                  const float* __restrict__ cb,
                                                  float* __restrict__ out) {
  const int bx = blockIdx.x;
  const int b = bx >> 10;
  const int rem = bx & 1023;
  const int c = rem >> 2;
  const int q = rem & 3;
  const int hw = q * 256 + threadIdx.x;
  const int id = (int)outids[b * HW + hw];
  out[((size_t)(b * CD + c)) * HW + hw] = cb[(size_t)id * CD + c];
}

extern "C" void kernel_launch(void* const* d_in, const int* in_sizes, int n_in,
                              void* d_out, int out_size, void* d_ws, size_t ws_size,
                              hipStream_t stream) {
  const float* x  = (const float*)d_in[0];   // (32,256,32,32) f32
  const float* cb = (const float*)d_in[1];   // (4096,256) f32
  float* out = (float*)d_out;                // [0..32767]=ids, [32768..]=emb (B,C,H,W)

  float* se = (float*)d_ws;                  // 16 KB

  vq_se<<<128, 256, 0, stream>>>(cb, se);
  vq_dist<<<1024, 256, 0, stream>>>(x, cb, se, out);
  vq_emb_out<<<32768, 256, 0, stream>>>(out, cb, out + NRW);
}

// Round 5
// 3688.433 us; speedup vs baseline: 3.4632x; 3.4632x over previous
//
#include <hip/hip_runtime.h>
#include <cfloat>

#define NRW 32768
#define KC 4096
#define CD 256
#define HW 1024

// exact numpy fp32 MAC: mul and add separately rounded (contract off in kernel)
#define MAC4(accv, xv, ev) do { \
  float p0 = (xv).x * (ev).x; (accv).x = (accv).x + p0; \
  float p1 = (xv).y * (ev).y; (accv).y = (accv).y + p1; \
  float p2 = (xv).z * (ev).z; (accv).z = (accv).z + p2; \
  float p3 = (xv).w * (ev).w; (accv).w = (accv).w + p3; } while (0)

// ---------- se[k] = np.sum(cb[k]**2) : numpy pairwise (128+128, scalar 8-acc) ----------
__global__ __launch_bounds__(256) void vq_se(const float* __restrict__ cb,
                                             float* __restrict__ se) {
#pragma clang fp contract(off)
  const int tid = threadIdx.x;
  const int g = tid >> 3;
  const int j = tid & 7;
  const int code = blockIdx.x * 32 + g;
  const float* e = cb + (size_t)code * CD;
  float half[2];
#pragma unroll
  for (int h = 0; h < 2; ++h) {
    const float* a = e + h * 128;
    float v = a[j];
    float r = v * v;
#pragma unroll
    for (int i = 1; i < 16; ++i) {
      float w = a[8 * i + j];
      float w2 = w * w;
      r = r + w2;
    }
    float l1 = r + __shfl_down(r, 1, 8);
    float l2 = l1 + __shfl_down(l1, 2, 8);
    float l3 = l2 + __shfl_down(l2, 4, 8);
    half[h] = l3;
  }
  if (j == 0) se[code] = half[0] + half[1];
}

// swizzled x LDS address: row r, channel c -> depth-8 optimal column reads
__device__ __forceinline__ int xaddr(int r, int c) {
  return r * 256 + ((((c >> 2) ^ (r & 7)) << 2) | (c & 3));
}

// ---------- main: lane=row, wave=code-quarter, e via uniform (scalar) loads ----------
__global__ __launch_bounds__(256) void vq_dist(const float* __restrict__ x,
                                               const float* __restrict__ cb,
                                               const float* __restrict__ se,
                                               float* __restrict__ outids) {
#pragma clang fp contract(off)
  __shared__ float xs[64 * 256];    // 64 KB; reused for the final merge

  const int tid = threadIdx.x;
  const int l   = tid & 63;         // lane = row
  const int w   = tid >> 6;         // wave = code quarter
  const int b   = blockIdx.x >> 4;
  const int hw0 = (blockIdx.x & 15) << 6;
  const float* xb = x + (size_t)b * CD * HW + hw0;

  // ---- stage x: thread = channel, 16 float4 over 64 rows ----
  {
    const float* src = xb + (size_t)tid * HW;
#pragma unroll
    for (int f = 0; f < 16; ++f) {
      const float4 v = *(const float4*)(src + 4 * f);
      xs[xaddr(4 * f + 0, tid)] = v.x;
      xs[xaddr(4 * f + 1, tid)] = v.y;
      xs[xaddr(4 * f + 2, tid)] = v.z;
      xs[xaddr(4 * f + 3, tid)] = v.w;
    }
  }
  __syncthreads();

  // ---- sx for own row: numpy pairwise (128+128, scalar 8-acc), serial per lane ----
  float sx;
  {
    float half[2];
#pragma unroll
    for (int h = 0; h < 2; ++h) {
      float racc[8];
#pragma unroll
      for (int j = 0; j < 8; ++j) {
        const float v = xs[xaddr(l, h * 128 + j)];
        racc[j] = v * v;
      }
#pragma unroll
      for (int i = 1; i < 16; ++i) {
#pragma unroll
        for (int j = 0; j < 8; ++j) {
          const float v = xs[xaddr(l, h * 128 + 8 * i + j)];
          const float v2 = v * v;
          racc[j] = racc[j] + v2;
        }
      }
      half[h] = ((racc[0] + racc[1]) + (racc[2] + racc[3])) +
                ((racc[4] + racc[5]) + (racc[6] + racc[7]));
    }
    sx = half[0] + half[1];
  }

  const int kbase = w << 10;              // wave's 1024-code range
  const float* xrow = xs + l * 256;
  const int s = l & 7;

  float m1 = FLT_MAX;
  int   mi = 0;

#pragma unroll 1
  for (int kt = 0; kt < 128; ++kt) {
    float4 acc[8];
#pragma unroll
    for (int t = 0; t < 8; ++t) { acc[t].x = 0.f; acc[t].y = 0.f; acc[t].z = 0.f; acc[t].w = 0.f; }
    const float* e0 = cb + (size_t)(kbase + kt * 8) * CD;

#pragma unroll 1
    for (int cc = 0; cc < 8; ++cc) {
      float4 xf[8];
#pragma unroll
      for (int f = 0; f < 8; ++f)
        xf[f] = *(const float4*)(xrow + ((cc * 8 + (f ^ s)) << 2));
#pragma unroll
      for (int t = 0; t < 8; ++t) {
        const float* ept = e0 + t * CD + cc * 32;   // wave-uniform -> scalar loads
        float4 ev;
        // numpy block order: B ascending, j = 3..0 within block (locked bit-exact)
        ev = *(const float4*)(ept + 12); MAC4(acc[t], xf[3], ev);
        ev = *(const float4*)(ept + 8);  MAC4(acc[t], xf[2], ev);
        ev = *(const float4*)(ept + 4);  MAC4(acc[t], xf[1], ev);
        ev = *(const float4*)(ept + 0);  MAC4(acc[t], xf[0], ev);
        ev = *(const float4*)(ept + 28); MAC4(acc[t], xf[7], ev);
        ev = *(const float4*)(ept + 24); MAC4(acc[t], xf[6], ev);
        ev = *(const float4*)(ept + 20); MAC4(acc[t], xf[5], ev);
        ev = *(const float4*)(ept + 16); MAC4(acc[t], xf[4], ev);
      }
    }

    // finish 8 dots: SSE tree, sq = se+sx, dist = sq - 2*dot; first-min (k ascends)
#pragma unroll
    for (int t = 0; t < 8; ++t) {
      const float dot  = (acc[t].x + acc[t].y) + (acc[t].z + acc[t].w);
      const float sq   = se[kbase + kt * 8 + t] + sx;
      const float td   = 2.0f * dot;
      const float dist = sq - td;
      const int k = kbase + kt * 8 + t;
      if (dist < m1) { m1 = dist; mi = k; }
    }
  }

  // ---- merge 4 waves per row (xs is dead; overlay) ----
  __syncthreads();
  float* ms  = xs;                 // [4][64]
  int*   mis = (int*)(xs + 256);   // [4][64]
  ms[w * 64 + l]  = m1;
  mis[w * 64 + l] = mi;
  __syncthreads();
  if (tid < 64) {
    float best = ms[tid];
    int   bi   = mis[tid];
#pragma unroll
    for (int ww = 1; ww < 4; ++ww) {
      const float v  = ms[ww * 64 + tid];
      const int   ix = mis[ww * 64 + tid];
      if (v < best || (v == best && ix < bi)) { best = v; bi = ix; }
    }
    outids[b * HW + hw0 + tid] = (float)bi;
  }
}

// ---------- emb gather ----------
__global__ __launch_bounds__(256) void vq_emb_out(const float* __restrict__ outids,
                                                  const float* __restrict__ cb,
                                                  float* __restrict__ out) {
  const int bx = blockIdx.x;
  const int b = bx >> 10;
  const int rem = bx & 1023;
  const int c = rem >> 2;
  const int q = rem & 3;
  const int hw = q * 256 + threadIdx.x;
  const int id = (int)outids[b * HW + hw];
  out[((size_t)(b * CD + c)) * HW + hw] = cb[(size_t)id * CD + c];
}

extern "C" void kernel_launch(void* const* d_in, const int* in_sizes, int n_in,
                              void* d_out, int out_size, void* d_ws, size_t ws_size,
                              hipStream_t stream) {
  const float* x  = (const float*)d_in[0];   // (32,256,32,32) f32
  const float* cb = (const float*)d_in[1];   // (4096,256) f32
  float* out = (float*)d_out;                // [0..32767]=ids, [32768..]=emb (B,C,H,W)

  float* se = (float*)d_ws;                  // 16 KB

  vq_se<<<128, 256, 0, stream>>>(cb, se);
  vq_dist<<<512, 256, 0, stream>>>(x, cb, se, out);
  vq_emb_out<<<32768, 256, 0, stream>>>(out, cb, out + NRW);
}